// Round 5
// baseline (184.079 us; speedup 1.0000x reference)
//
#include <hip/hip_runtime.h>

// DropConnect training path:
//   y[n,o] = 2 * ( sum_k x[n,k]*W[k,o]*wm[n,k,o] + b[o]*bm[n,o] )
// N=256, IN_DIM=1024, OUT_DIM=1024. Memory-bound on w_mask (1.07 GB, read once).
//
// R5: R4 + XCD-aware swizzle for weight L2 locality. Blocks sharing an
// o-quarter read the same 1 MB weight slice; pin each o-quarter to one XCD
// pair (xcd = oq*2 + (n&1), bid = (n>>1)*8 + xcd, using bid%8 -> XCD
// round-robin). Each XCD's L2 then holds 1 MB of weight instead of needing
// all 4 MB while 1 GB of nt-streamed mask evicts it -> weight HBM re-fetch
// ~eliminated. Inner loop / occupancy identical to R4 (32 waves/CU).

constexpr int N_      = 256;
constexpr int IN_DIM  = 1024;
constexpr int OUT_DIM = 1024;
constexpr int O4      = OUT_DIM / 4;     // 256 float4 columns per sample
constexpr int OQ4     = O4 / 4;          // 64 float4 columns per block
constexpr int KSPLIT  = 4;
constexpr int KCHUNK  = IN_DIM / KSPLIT; // 256

typedef float f32x4 __attribute__((ext_vector_type(4)));

__global__ __launch_bounds__(256, 8) void dropconnect_kernel(
    const float* __restrict__ x,       // [N, IN_DIM]
    const float* __restrict__ weight,  // [IN_DIM, OUT_DIM]
    const float* __restrict__ bias,    // [OUT_DIM]
    const float* __restrict__ w_mask,  // [N, IN_DIM, OUT_DIM]
    const float* __restrict__ b_mask,  // [N, OUT_DIM]
    float* __restrict__ out)           // [N, OUT_DIM]
{
    __shared__ f32x4 red[256];         // 4 KB

    // XCD-aware de-swizzle: bid%8 is the XCD. xcd = oq*2 + (n&1).
    const int bid    = blockIdx.x;
    const int xcd    = bid & 7;
    const int p      = bid >> 3;       // 0..127
    const int oq     = xcd >> 1;       // o-quarter 0..3
    const int parity = xcd & 1;
    const int n      = (p << 1) | parity;  // sample 0..255

    const int t   = threadIdx.x;       // 0..255
    const int ks  = t >> 6;            // k-quarter 0..3 == wave id (wave-uniform)
    const int c4  = (t & 63) + oq * OQ4;   // float4 column 0..255

    const size_t base4 = ((size_t)n * IN_DIM + (size_t)ks * KCHUNK) * O4;
    const f32x4* __restrict__ wm = reinterpret_cast<const f32x4*>(w_mask) + base4 + c4;
    const f32x4* __restrict__ wt = reinterpret_cast<const f32x4*>(weight) + (size_t)ks * KCHUNK * O4 + c4;
    const float* __restrict__ xr = x + n * IN_DIM + ks * KCHUNK;

    f32x4 acc = {0.f, 0.f, 0.f, 0.f};

    #pragma unroll 4
    for (int k = 0; k < KCHUNK; ++k) {
        const float xv = xr[k];                               // wave-uniform
        const f32x4 m = __builtin_nontemporal_load(wm + (size_t)k * O4);
        const f32x4 w = wt[k * O4];                           // L2-resident (1 MB/XCD now)
        acc[0] = fmaf(xv * w[0], m[0], acc[0]);
        acc[1] = fmaf(xv * w[1], m[1], acc[1]);
        acc[2] = fmaf(xv * w[2], m[2], acc[2]);
        acc[3] = fmaf(xv * w[3], m[3], acc[3]);
    }

    red[t] = acc;
    __syncthreads();

    if (t < 64) {
        const f32x4 a0 = red[t];
        const f32x4 a1 = red[t + 64];
        const f32x4 a2 = red[t + 128];
        const f32x4 a3 = red[t + 192];

        const int oc = oq * OQ4 + t;   // this thread's float4 column
        const f32x4 bm = reinterpret_cast<const f32x4*>(b_mask)[n * O4 + oc];
        const f32x4 bs = reinterpret_cast<const f32x4*>(bias)[oc];
        f32x4 r;
        r[0] = 2.0f * ((a0[0] + a1[0]) + (a2[0] + a3[0]) + bs[0] * bm[0]);
        r[1] = 2.0f * ((a0[1] + a1[1]) + (a2[1] + a3[1]) + bs[1] * bm[1]);
        r[2] = 2.0f * ((a0[2] + a1[2]) + (a2[2] + a3[2]) + bs[2] * bm[2]);
        r[3] = 2.0f * ((a0[3] + a1[3]) + (a2[3] + a3[3]) + bs[3] * bm[3]);
        reinterpret_cast<f32x4*>(out)[n * O4 + oc] = r;
    }
}

extern "C" void kernel_launch(void* const* d_in, const int* in_sizes, int n_in,
                              void* d_out, int out_size, void* d_ws, size_t ws_size,
                              hipStream_t stream) {
    const float* x      = (const float*)d_in[0];
    const float* weight = (const float*)d_in[1];
    const float* bias   = (const float*)d_in[2];
    const float* w_mask = (const float*)d_in[3];
    const float* b_mask = (const float*)d_in[4];
    float* out = (float*)d_out;

    dim3 grid(N_ * 4);
    dim3 block(256);
    dropconnect_kernel<<<grid, block, 0, stream>>>(x, weight, bias, w_mask, b_mask, out);
}